// Round 12
// baseline (639.896 us; speedup 1.0000x reference)
//
#include <hip/hip_runtime.h>
#include <stdint.h>

#define EPS 1e-5f

typedef __attribute__((ext_vector_type(8))) __bf16 bf16x8;
typedef __attribute__((ext_vector_type(16))) float f32x16;

__device__ __forceinline__ int swz4(int r) { return (r ^ (r >> 2)) & 3; }

__device__ __forceinline__ unsigned short f2bf(float f) {
  union { float f; unsigned u; } v; v.f = f;
  unsigned r = v.u + 0x7fffu + ((v.u >> 16) & 1u);
  return (unsigned short)(r >> 16);
}

__device__ __forceinline__ void glds16(const unsigned short* g, unsigned short* l) {
  __builtin_amdgcn_global_load_lds(
      (const __attribute__((address_space(1))) void*)g,
      (__attribute__((address_space(3))) void*)l, 16, 0, 0);
}
__device__ __forceinline__ void glds4(const unsigned short* g, unsigned short* l) {
  __builtin_amdgcn_global_load_lds(
      (const __attribute__((address_space(1))) void*)g,
      (__attribute__((address_space(3))) void*)l, 4, 0, 0);
}

template <int N>
__device__ __forceinline__ void vmwait() {
  asm volatile("s_waitcnt vmcnt(%0)" ::"n"(N) : "memory");
}

// ---------------------------------------------------------------------------
// Pack W [c2][c1][13][13] f32 -> bf16 per-K-step tiles = exact linear LDS
// image of the A tile (chunk swizzle baked in).
// K order: k = ((kh*8 + c1c)*13 + kw)*32 + c1i
// ---------------------------------------------------------------------------
__global__ __launch_bounds__(256) void pack_w_kernel(
    const float* __restrict__ W, unsigned short* __restrict__ Wp) {
  const int blk = blockIdx.x;  // c2*13 + kh
  const int c2 = blk / 13, kh = blk - c2 * 13;
  const int c1 = threadIdx.x;
  const int c2t = c2 >> 7, m = c2 & 127;
  const int c1c = c1 >> 5, c1i = c1 & 31;
  const float* src = W + (((size_t)(c2 * 256 + c1)) * 13 + kh) * 13;
  const int rowoff = (((c1i >> 3) ^ swz4(m)) << 3) + (c1i & 7);
#pragma unroll
  for (int kw = 0; kw < 13; ++kw) {
    const int ks = (kh * 8 + c1c) * 13 + kw;
    const size_t dst = (((size_t)c2t * 1352 + ks) * 128 + m) * 32 + rowoff;
    Wp[dst] = f2bf(src[kw]);
  }
}

// ---------------------------------------------------------------------------
// Pack x [b][c1][64][64] f32 -> xT[b][c1c][rowp 76][colp 80][c1i 32] bf16,
// zero-padded halo (rowp = row+6, colp = ic+8), chunk swizzle baked in.
// ---------------------------------------------------------------------------
__global__ __launch_bounds__(256) void pack_xt_kernel(
    const float* __restrict__ x, unsigned short* __restrict__ xT) {
  const int blk = blockIdx.x;  // (b*8 + c1c)*76 + rowp ; 4864 blocks
  const int rowp = blk % 76;
  const int bc = blk / 76;
  const int c1c = bc & 7, b = bc >> 3;
  const int row = rowp - 6;
  const bool rok = (unsigned)row < 64u;
  unsigned short* dst = xT + (size_t)blk * 2560;
  const float* srcb = x + (size_t)(b * 256 + c1c * 32) * 4096 +
                      (rok ? row * 64 : 0);
#pragma unroll
  for (int e = 0; e < 10; ++e) {
    const int idx = e * 256 + threadIdx.x;  // 0..2559
    const int colp = idx >> 5, c1i = idx & 31;
    const int ic = colp - 8;
    const float v = (rok && (unsigned)ic < 64u) ? srcb[(size_t)c1i * 4096 + ic] : 0.f;
    dst[colp * 32 + ((((c1i >> 3) ^ swz4(colp)) << 3)) + (c1i & 7)] = f2bf(v);
  }
}

// ---------------------------------------------------------------------------
// Implicit-GEMM conv + BN + SiLU.  (long phases: 3-4 kw-steps per barrier)
// Block: 256 thr (4 waves 2M x 2N), tile 128 c2 x 128 sp (2h x 64w).
// Wave tile 64x64, 32x32x16 MFMA. Grid 512 -> 2 independent blocks/CU.
// Per tile (13 steps): 4 phases {A:3, B:4, C:3, D:3}.  Phase p:
//   { A-glds(next phase, depth-1) ; W-round ; f0 reads ;
//     read f1 || MFMA f0 ; read f2 || MFMA f1 ; ... ; MFMA flast ;
//     vmwait<0> ; s_barrier }
// A LDS: asymmetric dbuf — par0 24 KiB (A,C), par1 32 KiB (B,D).
// ---------------------------------------------------------------------------
__global__ __launch_bounds__(256, 2) void conv12_kernel(
    const unsigned short* __restrict__ Wp, const unsigned short* __restrict__ xT,
    const float* __restrict__ gamma, const float* __restrict__ beta,
    const float* __restrict__ mean, const float* __restrict__ var,
    float* __restrict__ out) {
  __shared__ __align__(16) unsigned short Abuf[28672];    // 24 KiB + 32 KiB
  __shared__ __align__(16) unsigned short Wbuf[2][5120];  // 2 x 10 KiB
  __shared__ float s_scale[128], s_shift[128];

  const int tid = threadIdx.x;
  const int bid = blockIdx.x;
  const int b = bid & 7;  // XCD-aware: blocks on XCD k share batch image k
  const int h0 = ((bid >> 3) & 31) * 2;
  const int c2t = bid >> 8;

  const int wid = tid >> 6, lane = tid & 63;
  const int wr = wid >> 1, wc = wid & 1;
  const int l31 = lane & 31, hi2 = lane >> 5;

  if (tid < 128) {
    const int c2 = c2t * 128 + tid;
    const float inv = gamma[c2] * rsqrtf(var[c2] + EPS);
    s_scale[tid] = inv;
    s_shift[tid] = beta[c2] - mean[c2] * inv;
  }

  int aoffs[2][2];  // byte offsets within one 8 KiB step tile
#pragma unroll
  for (int mt = 0; mt < 2; ++mt)
#pragma unroll
    for (int ks = 0; ks < 2; ++ks) {
      const int m = wr * 64 + mt * 32 + l31;
      aoffs[mt][ks] = m * 64 + (((ks * 2 + hi2) ^ swz4(m)) << 4);
    }
  int ndh[2], nwl[2];
#pragma unroll
  for (int nt = 0; nt < 2; ++nt) {
    const int n = wc * 64 + nt * 32 + l31;
    ndh[nt] = n >> 6;
    nwl[nt] = n & 63;
  }

  const int tid8 = tid * 8, tid2 = tid * 2;
  const int widA = wid * 512, wid128 = wid * 128;

  const size_t c2base = (size_t)c2t * 1352;
  const int bc8 = b * 8;
  const char* Abase = (const char*)&Abuf[0];
  unsigned short* AbaseU = &Abuf[0];

  auto wtile = [&](int T) -> const unsigned short* {
    const int kh = T >> 3, c1c = T & 7;
    return xT + (size_t)((bc8 + c1c) * 76 + h0 + kh) * 2560;
  };

  f32x16 acc[2][2];
#pragma unroll
  for (int i = 0; i < 2; ++i)
#pragma unroll
    for (int j = 0; j < 2; ++j)
#pragma unroll
      for (int r = 0; r < 16; ++r) acc[i][j][r] = 0.f;

  // named fragment sets (static indexing; <=3 live at a time)
  bf16x8 fA0[2][2], fB0[2][2], fA1[2][2], fB1[2][2];
  bf16x8 fA2[2][2], fB2[2][2], fA3[2][2], fB3[2][2];

  unsigned short* wcurU = &Wbuf[0][0];
  unsigned short* wnxtU = &Wbuf[1][0];
  const char* wbC = (const char*)wcurU;

  // ---- prologue: W(tile0) -> Wbuf[0] (4 rounds); A phase-A (ks 0..2) -> par0
  {
    const unsigned short* ws = wtile(0);
    glds16(ws + tid8, wcurU + widA);
    glds16(ws + 2048 + tid8, wcurU + 2048 + widA);
    glds4(ws + 4096 + tid2, wcurU + 4096 + wid128);
    glds4(ws + 4608 + tid2, wcurU + 4608 + wid128);
#pragma unroll
    for (int i = 0; i < 3; ++i) {
      const unsigned short* at = Wp + ((c2base + (size_t)i) << 12);
      glds16(at + tid8, AbaseU + i * 4096 + widA);
      glds16(at + 2048 + tid8, AbaseU + i * 4096 + 2048 + widA);
    }
    vmwait<0>();
    __builtin_amdgcn_s_barrier();
    __builtin_amdgcn_sched_barrier(0);
  }

#define READF(FA, FB, ABOFF, KW)                                              \
  {                                                                           \
    const char* ab_ = Abase + 2 * (ABOFF);                                    \
    _Pragma("unroll") for (int ks = 0; ks < 2; ++ks) {                        \
      FA[ks][0] = *(const bf16x8*)(ab_ + aoffs[0][ks]);                       \
      FA[ks][1] = *(const bf16x8*)(ab_ + aoffs[1][ks]);                       \
      _Pragma("unroll") for (int nt = 0; nt < 2; ++nt) {                      \
        const int c_ = nwl[nt] + (KW) + 2;                                    \
        FB[ks][nt] = *(const bf16x8*)(wbC + (ndh[nt] * 80 + c_) * 64 +        \
                                      (((ks * 2 + hi2) ^ swz4(c_)) << 4));    \
      }                                                                       \
    }                                                                         \
  }

#define MF(FA, FB)                                                            \
  _Pragma("unroll") for (int ks = 0; ks < 2; ++ks) {                          \
    acc[0][0] = __builtin_amdgcn_mfma_f32_32x32x16_bf16(FA[ks][0], FB[ks][0], \
                                                        acc[0][0], 0, 0, 0);  \
    acc[0][1] = __builtin_amdgcn_mfma_f32_32x32x16_bf16(FA[ks][0], FB[ks][1], \
                                                        acc[0][1], 0, 0, 0);  \
    acc[1][0] = __builtin_amdgcn_mfma_f32_32x32x16_bf16(FA[ks][1], FB[ks][0], \
                                                        acc[1][0], 0, 0, 0);  \
    acc[1][1] = __builtin_amdgcn_mfma_f32_32x32x16_bf16(FA[ks][1], FB[ks][1], \
                                                        acc[1][1], 0, 0, 0);  \
  }

// prefetch NN steps starting at global k-step KS0 into Abuf region NABASE
#define PREA(NN, KS0, NABASE)                                                 \
  _Pragma("unroll") for (int i = 0; i < (NN); ++i) {                          \
    const unsigned short* at =                                                \
        Wp + ((c2base + (size_t)((KS0) + i)) << 12);                          \
    unsigned short* ad = AbaseU + (NABASE) + i * 4096;                        \
    glds16(at + tid8, ad + widA);                                             \
    glds16(at + 2048 + tid8, ad + 2048 + widA);                               \
  }

#define ENDPH                                                                 \
  vmwait<0>();                                                                \
  __builtin_amdgcn_s_barrier();                                               \
  __builtin_amdgcn_sched_barrier(0);

  for (int t = 0; t < 104; ++t) {
    const int t13 = t * 13;
    const int tn = (t == 103) ? 0 : t + 1;
    const int tn13 = tn * 13;
    const unsigned short* wsrc = wtile(tn);

    // ---- phase A: steps kw 0..2 @par0(0); prefetch B (4, t13+3) -> par1
    PREA(4, t13 + 3, 12288)
    glds16(wsrc + tid8, wnxtU + widA);  // W round 1
    READF(fA0, fB0, 0, 0)
    __builtin_amdgcn_s_setprio(1);
    READF(fA1, fB1, 4096, 1)
    MF(fA0, fB0)
    READF(fA2, fB2, 8192, 2)
    MF(fA1, fB1)
    MF(fA2, fB2)
    __builtin_amdgcn_s_setprio(0);
    ENDPH

    // ---- phase B: steps kw 3..6 @par1(12288); prefetch C (3, t13+7) -> par0
    PREA(3, t13 + 7, 0)
    glds16(wsrc + 2048 + tid8, wnxtU + 2048 + widA);  // W round 2
    READF(fA0, fB0, 12288, 3)
    __builtin_amdgcn_s_setprio(1);
    READF(fA1, fB1, 16384, 4)
    MF(fA0, fB0)
    READF(fA2, fB2, 20480, 5)
    MF(fA1, fB1)
    READF(fA3, fB3, 24576, 6)
    MF(fA2, fB2)
    MF(fA3, fB3)
    __builtin_amdgcn_s_setprio(0);
    ENDPH

    // ---- phase C: steps kw 7..9 @par0; prefetch D (3, t13+10) -> par1
    PREA(3, t13 + 10, 12288)
    glds4(wsrc + 4096 + tid2, wnxtU + 4096 + wid128);  // W rounds 3+4
    glds4(wsrc + 4608 + tid2, wnxtU + 4608 + wid128);
    READF(fA0, fB0, 0, 7)
    __builtin_amdgcn_s_setprio(1);
    READF(fA1, fB1, 4096, 8)
    MF(fA0, fB0)
    READF(fA2, fB2, 8192, 9)
    MF(fA1, fB1)
    MF(fA2, fB2)
    __builtin_amdgcn_s_setprio(0);
    ENDPH

    // ---- phase D: steps kw 10..12 @par1; prefetch A' (3, tn13) -> par0
    PREA(3, tn13, 0)
    READF(fA0, fB0, 12288, 10)
    __builtin_amdgcn_s_setprio(1);
    READF(fA1, fB1, 16384, 11)
    MF(fA0, fB0)
    READF(fA2, fB2, 20480, 12)
    MF(fA1, fB1)
    MF(fA2, fB2)
    __builtin_amdgcn_s_setprio(0);
    ENDPH

    // swap W buffers
    unsigned short* tw = wcurU;
    wcurU = wnxtU;
    wnxtU = tw;
    wbC = (const char*)wcurU;
  }
#undef READF
#undef MF
#undef PREA
#undef ENDPH

  // ---- epilogue: BN + SiLU.
  // 32x32 C/D layout (m74/m101): col = lane&31, row = (r&3)+8*(r>>2)+4*(lane>>5)
#pragma unroll
  for (int mt = 0; mt < 2; ++mt) {
#pragma unroll
    for (int nt = 0; nt < 2; ++nt) {
      const int n = wc * 64 + nt * 32 + l31;
      const int hh = h0 + (n >> 6), ww = n & 63;
#pragma unroll
      for (int r = 0; r < 16; ++r) {
        const int mloc = (r & 3) + 8 * (r >> 2) + 4 * hi2;
        const int c2l = wr * 64 + mt * 32 + mloc;
        const float y = acc[mt][nt][r] * s_scale[c2l] + s_shift[c2l];
        out[((size_t)(b * 256 + c2t * 128 + c2l)) * 4096 + hh * 64 + ww] =
            y / (1.f + __expf(-y));
      }
    }
  }
}

// ---------------------------------------------------------------------------
// Safety-net fallback if workspace is too small for packed buffers.
// ---------------------------------------------------------------------------
__global__ void naive_conv_kernel(
    const float* __restrict__ x, const float* __restrict__ W,
    const float* __restrict__ gamma, const float* __restrict__ beta,
    const float* __restrict__ mean, const float* __restrict__ var,
    float* __restrict__ out) {
  const int idx = blockIdx.x * 256 + threadIdx.x;
  if (idx >= 8 * 256 * 64 * 64) return;
  const int w = idx & 63, h = (idx >> 6) & 63;
  const int c2 = (idx >> 12) & 255, b = idx >> 20;
  float s = 0.f;
  for (int c1 = 0; c1 < 256; ++c1) {
    const float* xp = x + ((size_t)(b * 256 + c1) * 4096);
    const float* wp = W + ((size_t)(c2 * 256 + c1) * 169);
    for (int kh = 0; kh < 13; ++kh) {
      const int r = h + kh - 6;
      if ((unsigned)r >= 64u) continue;
      for (int kw = 0; kw < 13; ++kw) {
        const int c = w + kw - 6;
        if ((unsigned)c >= 64u) continue;
        s += xp[r * 64 + c] * wp[kh * 13 + kw];
      }
    }
  }
  const float inv = gamma[c2] * rsqrtf(var[c2] + EPS);
  const float y = s * inv + (beta[c2] - mean[c2] * inv);
  out[idx] = y / (1.f + __expf(-y));
}

extern "C" void kernel_launch(void* const* d_in, const int* in_sizes, int n_in,
                              void* d_out, int out_size, void* d_ws, size_t ws_size,
                              hipStream_t stream) {
  const float* x = (const float*)d_in[0];
  const float* W = (const float*)d_in[1];
  const float* gamma = (const float*)d_in[2];
  const float* beta = (const float*)d_in[3];
  const float* mean = (const float*)d_in[4];
  const float* var = (const float*)d_in[5];
  float* out = (float*)d_out;

  const size_t WP_BYTES = (size_t)256 * 43264 * 2;  // 22,151,168
  const size_t XT_BYTES = (size_t)12455424 * 2;     // 24,910,848

  if (ws_size >= WP_BYTES + XT_BYTES) {
    unsigned short* Wp = (unsigned short*)d_ws;
    unsigned short* xT = (unsigned short*)((char*)d_ws + WP_BYTES);
    pack_w_kernel<<<256 * 13, 256, 0, stream>>>(W, Wp);
    pack_xt_kernel<<<8 * 8 * 76, 256, 0, stream>>>(x, xT);
    conv12_kernel<<<512, 256, 0, stream>>>(Wp, xT, gamma, beta, mean, var, out);
  } else {
    naive_conv_kernel<<<(8 * 256 * 64 * 64 + 255) / 256, 256, 0, stream>>>(
        x, W, gamma, beta, mean, var, out);
  }
}